// Round 3
// baseline (192.845 us; speedup 1.0000x reference)
//
#include <hip/hip_runtime.h>
#include <hip/hip_fp16.h>
#include <math.h>

// ---------------------------------------------------------------------------
// GCN encoder. Aggregation = gather over a single-pass device-built ELL table:
//   k_scatter: r = atomicAdd(&cnt[c],1); ell[c*48+r] = src_row_byte_offset
// v2: XCD-sliced scatter (slice = blockIdx&7 -> per-XCD L2-resident ell slice).
// v3: 8-byte gather loads; dinv recomputed from cnt; 5 launches.
// v4: 16-byte gather loads (8 lanes x uint4 per 128B row, 8 edge groups/wave)
//     -> 8 VMEM instr per 8-edge step (was 12), 1KB/row-load instruction;
//     row prefetch depth 2 (was 1), idx depth 3 -> ~2x bytes in flight.
// Rows are pre-scaled fp16: hs[r] = dinv[r]*(x@W1)[r], h2s[r] = dinv[r]*h2[r];
// self loop is handled by initializing the accumulator from the node's own row.
// Gather entries beyond exact degree are clamped (cndmask) to a zero row.
// ---------------------------------------------------------------------------

#define ELLW 48

typedef _Float16 half8 __attribute__((ext_vector_type(8)));
typedef float f32x4 __attribute__((ext_vector_type(4)));

// Pack W1 into f16 B-frag layout (4 col-tiles x 4 k-steps) and [W2|W3] into
// 5 tiles x 2 k-steps; blocks >= 52 zero the cnt array.
__global__ void k_setup(const float* __restrict__ W1, const float* __restrict__ W2,
                        const float* __restrict__ W3, _Float16* __restrict__ W1g,
                        _Float16* __restrict__ Bg, int* __restrict__ cnt, int n) {
    if (blockIdx.x >= 52) {
        int i = (blockIdx.x - 52) * 256 + threadIdx.x;
        if (i < n) cnt[i] = 0;
        return;
    }
    int idx = blockIdx.x * 256 + threadIdx.x;
    if (idx < 8192) {
        int j = idx & 7, L = (idx >> 3) & 63, s = (idx >> 9) & 3, t = idx >> 11;
        int k = s * 32 + (L >> 4) * 8 + j;
        int c = t * 16 + (L & 15);
        W1g[idx] = (_Float16)W1[k * 64 + c];
    } else if (idx < 8192 + 5120) {
        int i2 = idx - 8192;
        int j = i2 & 7, L = (i2 >> 3) & 63, s = (i2 >> 9) & 1, u = i2 >> 10;
        int k = s * 32 + (L >> 4) * 8 + j;
        int c = (L & 15);
        float v;
        if (u < 4) v = W2[k * 64 + u * 16 + c];
        else v = (c < 6) ? W3[k * 6 + c] : 0.f;
        Bg[i2] = (_Float16)v;
    }
}

// XCD-sliced single-pass ELL build: rank comes from the atomic itself.
// slice = blockIdx&7 -> round-robin XCD mapping; each slice's cnt+ell working
// set (~25KB + ~1.2MB) stays resident in that XCD's L2 so writebacks merge.
__global__ __launch_bounds__(256) void k_scatter(
    const int* __restrict__ row, const int* __restrict__ col,
    int* __restrict__ cnt, int* __restrict__ ell, int E, int slice_sz) {
    int slice = blockIdx.x & 7;
    int lo = slice * slice_sz;
    int hi = lo + slice_sz;
    int nchunk = gridDim.x >> 3;
    int stride = nchunk * 256;
    int v0 = (blockIdx.x >> 3) * 256 + threadIdx.x;
    int nv = E >> 2;
    const int4* c4p = (const int4*)col;
    const int4* r4p = (const int4*)row;
    for (int v = v0; v < nv; v += stride) {
        int4 c4 = c4p[v];
        int4 r4 = r4p[v];
        if (c4.x >= lo && c4.x < hi) {
            int rk = atomicAdd(&cnt[c4.x], 1);
            if (rk < ELLW) ell[c4.x * ELLW + rk] = r4.x << 7;
        }
        if (c4.y >= lo && c4.y < hi) {
            int rk = atomicAdd(&cnt[c4.y], 1);
            if (rk < ELLW) ell[c4.y * ELLW + rk] = r4.y << 7;
        }
        if (c4.z >= lo && c4.z < hi) {
            int rk = atomicAdd(&cnt[c4.z], 1);
            if (rk < ELLW) ell[c4.z * ELLW + rk] = r4.z << 7;
        }
        if (c4.w >= lo && c4.w < hi) {
            int rk = atomicAdd(&cnt[c4.w], 1);
            if (rk < ELLW) ell[c4.w * ELLW + rk] = r4.w << 7;
        }
    }
    if ((blockIdx.x >> 3) == 0) {        // tail edges (E % 4)
        for (int e = (nv << 2) + threadIdx.x; e < E; e += 256) {
            int c = col[e];
            if (c >= lo && c < hi) {
                int rk = atomicAdd(&cnt[c], 1);
                if (rk < ELLW) ell[c * ELLW + rk] = row[e] << 7;
            }
        }
    }
}

// hs = (x @ W1) * dinv, via f16 MFMA. Block = 4 waves x 16 nodes = 64 nodes.
__global__ __launch_bounds__(256, 4) void k_gemm1(
    const float* __restrict__ x, const _Float16* __restrict__ W1g,
    const int* __restrict__ cnt, uint* __restrict__ hs,
    uint* __restrict__ h2s, int n) {
    int tid = threadIdx.x;
    if (blockIdx.x == 0) {               // zero rows for clamped gathers
        if (tid < 32) hs[(size_t)n * 32 + tid] = 0u;
        else if (tid < 64) h2s[(size_t)n * 32 + (tid - 32)] = 0u;
    }
    int lane = tid & 63, wid = tid >> 6;
    int m16 = lane & 15, quad = lane >> 4;
    int node0 = blockIdx.x * 64 + wid * 16;
    int arow = node0 + m16;
    if (arow >= n) arow = n - 1;
    const float* xr = x + (size_t)arow * 128;
    half8 A[4];
#pragma unroll
    for (int s = 0; s < 4; s++) {
        const float4* p = (const float4*)(xr + s * 32 + quad * 8);
        float4 f0 = p[0], f1 = p[1];
        half8 a;
        a[0] = (_Float16)f0.x; a[1] = (_Float16)f0.y;
        a[2] = (_Float16)f0.z; a[3] = (_Float16)f0.w;
        a[4] = (_Float16)f1.x; a[5] = (_Float16)f1.y;
        a[6] = (_Float16)f1.z; a[7] = (_Float16)f1.w;
        A[s] = a;
    }
    float dsc[4];
#pragma unroll
    for (int r = 0; r < 4; r++) {
        int nd = node0 + quad * 4 + r;
        dsc[r] = rsqrtf((float)(cnt[nd < n ? nd : n - 1] + 1));
    }
    const half8* Wv = (const half8*)W1g;
#pragma unroll
    for (int t = 0; t < 4; t++) {
        f32x4 acc = {0.f, 0.f, 0.f, 0.f};
#pragma unroll
        for (int s = 0; s < 4; s++)
            acc = __builtin_amdgcn_mfma_f32_16x16x32_f16(A[s], Wv[(t * 4 + s) * 64 + lane], acc, 0, 0, 0);
#pragma unroll
        for (int r = 0; r < 4; r++) {
            int nd = node0 + quad * 4 + r;
            float v = acc[r] * dsc[r];
            float vo = __shfl_xor(v, 1, 64);
            if (!(m16 & 1) && nd < n) {
                __half2 pk = __floats2half2_rn(v, vo);
                hs[(size_t)nd * 32 + t * 8 + (m16 >> 1)] = *(uint*)&pk;
            }
        }
    }
}

// ---------------------------------------------------------------------------
// v4 gather: lane = g*8 + l; l = byte-slice (16B of the 128B row), g = edge
// group in [0,8). Per 8-edge step per node: 1 idx load (4B, coalesced 32B per
// group-of-8) + 1 row load (uint4) per lane. Rows prefetched 2 steps ahead.
// accv[p][c] accumulates comps 8*l + c (f32). Cross-group reduce at the end.
// ---------------------------------------------------------------------------
#define GATHER_PROLOG(SRC_T)                                                  \
    int st[4], P[4], nid[4];                                                  \
    int Pmax = 0;                                                             \
    _Pragma("unroll") for (int p = 0; p < 4; p++) {                           \
        int node = base + wid * 4 + p;                                        \
        if (node >= n) node = n - 1;                                          \
        nid[p] = node; st[p] = node * ELLW; P[p] = cnt[node];                 \
        Pmax = Pmax > P[p] ? Pmax : P[p];                                     \
    }                                                                         \
    Pmax = (Pmax + 7) & ~7;                                                   \
    auto ldix = [&](int p, int jb) -> int {                                   \
        int o = ell[st[p] + jb + g];                                          \
        return (jb + g < P[p]) ? o : zoff;                                    \
    };                                                                        \
    const char* hsb = (const char*)(SRC_T);                                   \
    float accv[4][8];                                                         \
    _Pragma("unroll") for (int p = 0; p < 4; p++) {                           \
        int sa = (g == 0) ? (nid[p] << 7) : zoff;                             \
        uint4 us = *(const uint4*)(hsb + sa + m16b);                          \
        float2 f;                                                             \
        f = __half22float2(*(__half2*)&us.x); accv[p][0] = f.x; accv[p][1] = f.y; \
        f = __half22float2(*(__half2*)&us.y); accv[p][2] = f.x; accv[p][3] = f.y; \
        f = __half22float2(*(__half2*)&us.z); accv[p][4] = f.x; accv[p][5] = f.y; \
        f = __half22float2(*(__half2*)&us.w); accv[p][6] = f.x; accv[p][7] = f.y; \
    }

#define CVT_ACC(p, U)                                                         \
    {                                                                         \
        float2 f;                                                             \
        f = __half22float2(*(__half2*)&U.x); accv[p][0] += f.x; accv[p][1] += f.y; \
        f = __half22float2(*(__half2*)&U.y); accv[p][2] += f.x; accv[p][3] += f.y; \
        f = __half22float2(*(__half2*)&U.z); accv[p][4] += f.x; accv[p][5] += f.y; \
        f = __half22float2(*(__half2*)&U.w); accv[p][6] += f.x; accv[p][7] += f.y; \
    }

#define GATHER_BODY16(SRC)                                                    \
    {                                                                         \
        int oC[4], oD[4];                                                     \
        uint4 uA[4], uB[4], uC[4];                                            \
        {                                                                     \
            int oA[4], oB[4];                                                 \
            _Pragma("unroll") for (int p = 0; p < 4; p++) oA[p] = ldix(p, 0); \
            _Pragma("unroll") for (int p = 0; p < 4; p++) oB[p] = ldix(p, 8); \
            _Pragma("unroll") for (int p = 0; p < 4; p++) oC[p] = ldix(p, 16);\
            _Pragma("unroll") for (int p = 0; p < 4; p++)                     \
                uA[p] = *(const uint4*)(SRC + oA[p] + m16b);                  \
            _Pragma("unroll") for (int p = 0; p < 4; p++)                     \
                uB[p] = *(const uint4*)(SRC + oB[p] + m16b);                  \
        }                                                                     \
        for (int jb = 0; jb < Pmax; jb += 8) {                                \
            _Pragma("unroll") for (int p = 0; p < 4; p++) oD[p] = ldix(p, jb + 24); \
            _Pragma("unroll") for (int p = 0; p < 4; p++)                     \
                uC[p] = *(const uint4*)(SRC + oC[p] + m16b);                  \
            _Pragma("unroll") for (int p = 0; p < 4; p++) CVT_ACC(p, uA[p])   \
            _Pragma("unroll") for (int p = 0; p < 4; p++) {                   \
                uA[p] = uB[p]; uB[p] = uC[p]; oC[p] = oD[p];                  \
            }                                                                 \
        }                                                                     \
    }                                                                         \
    _Pragma("unroll") for (int p = 0; p < 4; p++)                             \
        _Pragma("unroll") for (int c = 0; c < 8; c++) {                       \
            float v = accv[p][c];                                             \
            v += __shfl_xor(v, 8, 64);                                        \
            v += __shfl_xor(v, 16, 64);                                       \
            v += __shfl_xor(v, 32, 64);                                       \
            accv[p][c] = v;                                                   \
        }

// conv1 + bias + LN + ReLU, then h2s & out2 via per-wave MFMA. No barriers.
__global__ __launch_bounds__(256, 4) void k_conv1_fused(
    const uint* __restrict__ hs, const int* __restrict__ ell,
    const int* __restrict__ cnt, const float* __restrict__ b1,
    const float* __restrict__ lnw_g, const float* __restrict__ lnb_g,
    const _Float16* __restrict__ Bg, const float* __restrict__ b3,
    uint* __restrict__ h2s, float* __restrict__ out2, int zoff, int n) {
    __shared__ _Float16 Y[4][16 * 72];   // per-wave A tile, stride 72
    int tid = threadIdx.x;
    int lane = tid & 63, wid = tid >> 6;
    int l = lane & 7, g = lane >> 3;
    int m16b = l * 16;
    {   // zero my wave's tile (rows 4..15 stay zero for the MFMA)
        float4 z = {0.f, 0.f, 0.f, 0.f};
        float4* yb = (float4*)Y[wid];
        for (int i = lane; i < 144; i += 64) yb[i] = z;
    }
    int base = blockIdx.x * 16;
    GATHER_PROLOG(hs)
    GATHER_BODY16(hsb)

    // LN + ReLU: lane owns comps 8l..8l+7 (duplicated across g); row reduce
    // is xor 1,2,4 (l bits). Write y rows (f16, 16B/lane from g==0) to Y tile.
    float4 bvlo = ((const float4*)b1)[2 * l], bvhi = ((const float4*)b1)[2 * l + 1];
    float4 lwlo = ((const float4*)lnw_g)[2 * l], lwhi = ((const float4*)lnw_g)[2 * l + 1];
    float4 lblo = ((const float4*)lnb_g)[2 * l], lbhi = ((const float4*)lnb_g)[2 * l + 1];
    float dcs[4];
#pragma unroll
    for (int p = 0; p < 4; p++) {
        float dc = rsqrtf((float)(P[p] + 1));
        dcs[p] = dc;
        float v[8];
        v[0] = fmaf(dc, accv[p][0], bvlo.x); v[1] = fmaf(dc, accv[p][1], bvlo.y);
        v[2] = fmaf(dc, accv[p][2], bvlo.z); v[3] = fmaf(dc, accv[p][3], bvlo.w);
        v[4] = fmaf(dc, accv[p][4], bvhi.x); v[5] = fmaf(dc, accv[p][5], bvhi.y);
        v[6] = fmaf(dc, accv[p][6], bvhi.z); v[7] = fmaf(dc, accv[p][7], bvhi.w);
        float s = ((v[0] + v[1]) + (v[2] + v[3])) + ((v[4] + v[5]) + (v[6] + v[7]));
        s += __shfl_xor(s, 1, 64); s += __shfl_xor(s, 2, 64); s += __shfl_xor(s, 4, 64);
        float mu = s * (1.f / 64.f);
        float d[8], q = 0.f;
#pragma unroll
        for (int c = 0; c < 8; c++) { d[c] = v[c] - mu; q += d[c] * d[c]; }
        q += __shfl_xor(q, 1, 64); q += __shfl_xor(q, 2, 64); q += __shfl_xor(q, 4, 64);
        float rstd = rsqrtf(q * (1.f / 64.f) + 1e-5f);
        float y[8];
        y[0] = fmaxf(fmaf(d[0] * rstd, lwlo.x, lblo.x), 0.f);
        y[1] = fmaxf(fmaf(d[1] * rstd, lwlo.y, lblo.y), 0.f);
        y[2] = fmaxf(fmaf(d[2] * rstd, lwlo.z, lblo.z), 0.f);
        y[3] = fmaxf(fmaf(d[3] * rstd, lwlo.w, lblo.w), 0.f);
        y[4] = fmaxf(fmaf(d[4] * rstd, lwhi.x, lbhi.x), 0.f);
        y[5] = fmaxf(fmaf(d[5] * rstd, lwhi.y, lbhi.y), 0.f);
        y[6] = fmaxf(fmaf(d[6] * rstd, lwhi.z, lbhi.z), 0.f);
        y[7] = fmaxf(fmaf(d[7] * rstd, lwhi.w, lbhi.w), 0.f);
        if (g == 0) {                    // 8 lanes x 16B = full 128B row
            __half2 pk0 = __floats2half2_rn(y[0], y[1]);
            __half2 pk1 = __floats2half2_rn(y[2], y[3]);
            __half2 pk2 = __floats2half2_rn(y[4], y[5]);
            __half2 pk3 = __floats2half2_rn(y[6], y[7]);
            uint4 pk;
            pk.x = *(uint*)&pk0; pk.y = *(uint*)&pk1;
            pk.z = *(uint*)&pk2; pk.w = *(uint*)&pk3;
            *(uint4*)&Y[wid][p * 72 + 8 * l] = pk;   // byte p*144+16l, 16B-aligned
        }
    }
    // same-wave LDS producer/consumer: lgkmcnt wait only, no barrier
    int m16 = lane & 15, quad = lane >> 4;
    half8 a0 = *(const half8*)&Y[wid][m16 * 72 + quad * 8];
    half8 a1 = *(const half8*)&Y[wid][m16 * 72 + 32 + quad * 8];
    const half8* Bv = (const half8*)Bg;
    _Float16* h2h = (_Float16*)h2s;
#pragma unroll
    for (int t = 0; t < 4; t++) {        // h2 = y @ W2 (4 col tiles)
        f32x4 acc2 = {0.f, 0.f, 0.f, 0.f};
        acc2 = __builtin_amdgcn_mfma_f32_16x16x32_f16(a0, Bv[(t * 2 + 0) * 64 + lane], acc2, 0, 0, 0);
        acc2 = __builtin_amdgcn_mfma_f32_16x16x32_f16(a1, Bv[(t * 2 + 1) * 64 + lane], acc2, 0, 0, 0);
#pragma unroll
        for (int r = 0; r < 4; r++) {    // C row quad*4+r: real rows live in quad 0
            int nodep = base + wid * 4 + r;
            if (quad == 0 && nodep < n)
                h2h[(size_t)nodep * 64 + t * 16 + m16] = (_Float16)(acc2[r] * dcs[r]);
        }
    }
    {                                    // out2 = sigmoid(y @ W3 + b3)
        f32x4 acc2 = {0.f, 0.f, 0.f, 0.f};
        acc2 = __builtin_amdgcn_mfma_f32_16x16x32_f16(a0, Bv[8 * 64 + lane], acc2, 0, 0, 0);
        acc2 = __builtin_amdgcn_mfma_f32_16x16x32_f16(a1, Bv[9 * 64 + lane], acc2, 0, 0, 0);
        float bb = b3[m16 < 6 ? m16 : 0];
#pragma unroll
        for (int r = 0; r < 4; r++) {
            int nodep = base + wid * 4 + r;
            if (quad == 0 && m16 < 6 && nodep < n)
                out2[(size_t)nodep * 6 + m16] = 1.f / (1.f + __expf(-(acc2[r] + bb)));
        }
    }
}

// conv2: out1 = dc * (self + sum(h2s[slice])) + b2.
__global__ __launch_bounds__(256, 4) void k_conv2(
    const uint* __restrict__ h2s, const int* __restrict__ ell,
    const int* __restrict__ cnt, const float* __restrict__ b2,
    float* __restrict__ out1, int zoff, int n) {
    int tid = threadIdx.x;
    int lane = tid & 63, wid = tid >> 6;
    int l = lane & 7, g = lane >> 3;
    int m16b = l * 16;
    int base = blockIdx.x * 16;
    GATHER_PROLOG(h2s)
    GATHER_BODY16(hsb)

    float4 b2lo = ((const float4*)b2)[2 * l], b2hi = ((const float4*)b2)[2 * l + 1];
#pragma unroll
    for (int p = 0; p < 4; p++) {
        int node = base + wid * 4 + p;
        if (g == 0 && node < n) {
            float dc = rsqrtf((float)(P[p] + 1));
            float4 r0, r1;
            r0.x = fmaf(dc, accv[p][0], b2lo.x);
            r0.y = fmaf(dc, accv[p][1], b2lo.y);
            r0.z = fmaf(dc, accv[p][2], b2lo.z);
            r0.w = fmaf(dc, accv[p][3], b2lo.w);
            r1.x = fmaf(dc, accv[p][4], b2hi.x);
            r1.y = fmaf(dc, accv[p][5], b2hi.y);
            r1.z = fmaf(dc, accv[p][6], b2hi.z);
            r1.w = fmaf(dc, accv[p][7], b2hi.w);
            ((float4*)out1)[(size_t)node * 16 + 2 * l] = r0;
            ((float4*)out1)[(size_t)node * 16 + 2 * l + 1] = r1;
        }
    }
}

extern "C" void kernel_launch(void* const* d_in, const int* in_sizes, int n_in,
                              void* d_out, int out_size, void* d_ws, size_t ws_size,
                              hipStream_t stream) {
    const float* x   = (const float*)d_in[0];
    const int*   ei  = (const int*)d_in[1];
    const float* W1  = (const float*)d_in[2];
    const float* b1  = (const float*)d_in[3];
    const float* lnw = (const float*)d_in[4];
    const float* lnb = (const float*)d_in[5];
    const float* W2  = (const float*)d_in[6];
    const float* b2  = (const float*)d_in[7];
    const float* W3  = (const float*)d_in[8];
    const float* b3  = (const float*)d_in[9];

    int n = in_sizes[0] / 128;
    int E = in_sizes[1] / 2;
    const int* row = ei;        // sources
    const int* col = ei + E;    // targets

    char* ws = (char*)d_ws;
    size_t off = 0;
    auto carve = [&](size_t bytes) -> char* {
        char* p = ws + off;
        off = (off + bytes + 255) & ~(size_t)255;
        return p;
    };
    int*   cnt  = (int*)carve(4 * (size_t)n);
    int*   ell  = (int*)carve(4 * ((size_t)n * ELLW + 256));  // +margin for prefetch
    uint*  hs   = (uint*)carve(128 * ((size_t)n + 1));        // +1 zero row
    uint*  h2s  = (uint*)carve(128 * ((size_t)n + 1));
    _Float16* W1g = (_Float16*)carve(2 * 8192);
    _Float16* Bg  = (_Float16*)carve(2 * 5120);

    float* out1 = (float*)d_out;
    float* out2 = out1 + (size_t)n * 64;
    int zero_off = n << 7;
    int slice_sz = (n + 7) / 8;          // contiguous node slice per XCD

    k_setup<<<52 + (n + 255) / 256, 256, 0, stream>>>(W1, W2, W3, W1g, Bg, cnt, n);
    // 8 slices x 256 edge-chunks; blockIdx&7 = slice -> XCD round-robin
    k_scatter<<<8 * 256, 256, 0, stream>>>(row, col, cnt, ell, E, slice_sz);
    k_gemm1<<<(n + 63) / 64, 256, 0, stream>>>(x, W1g, cnt, hs, h2s, n);
    k_conv1_fused<<<(n + 15) / 16, 256, 0, stream>>>(hs, ell, cnt,
                                                     b1, lnw, lnb, Bg, b3,
                                                     h2s, out2, zero_off, n);
    k_conv2<<<(n + 15) / 16, 256, 0, stream>>>(h2s, ell, cnt, b2,
                                               out1, zero_off, n);
}

// Round 5
// 192.458 us; speedup vs baseline: 1.0020x; 1.0020x over previous
//
#include <hip/hip_runtime.h>
#include <hip/hip_fp16.h>
#include <math.h>

// ---------------------------------------------------------------------------
// GCN encoder. Aggregation = gather over a single-pass device-built ELL table:
//   k_scatter: r = atomicAdd(&cnt[c],1); ell[c*48+r] = src_row_byte_offset
// v2: XCD-sliced scatter (slice = blockIdx&7 -> per-XCD L2-resident ell slice).
// v3: 8-byte gather loads; dinv recomputed from cnt; 5 launches.
// v4: 16-byte gather loads (8 lanes x uint4 per 128B row, 8 edge groups/wave)
//     + depth-2 prefetch -> REGRESSED (VGPR cliff at 128, ~125 peak).
// v5: 16-byte loads, depth-1 prefetch: 8 VMEM/8-edge-step (v3 had 12) at
//     v3-level register pressure (~105 VGPR). Isolates the issue-count lever.
//     (Resubmitted unchanged: round-4 bench died on GPU acquisition timeout.)
// Rows are pre-scaled fp16: hs[r] = dinv[r]*(x@W1)[r], h2s[r] = dinv[r]*h2[r];
// self loop is handled by initializing the accumulator from the node's own row.
// Gather entries beyond exact degree are clamped (cndmask) to a zero row.
// ---------------------------------------------------------------------------

#define ELLW 48

typedef _Float16 half8 __attribute__((ext_vector_type(8)));
typedef float f32x4 __attribute__((ext_vector_type(4)));

// Pack W1 into f16 B-frag layout (4 col-tiles x 4 k-steps) and [W2|W3] into
// 5 tiles x 2 k-steps; blocks >= 52 zero the cnt array.
__global__ void k_setup(const float* __restrict__ W1, const float* __restrict__ W2,
                        const float* __restrict__ W3, _Float16* __restrict__ W1g,
                        _Float16* __restrict__ Bg, int* __restrict__ cnt, int n) {
    if (blockIdx.x >= 52) {
        int i = (blockIdx.x - 52) * 256 + threadIdx.x;
        if (i < n) cnt[i] = 0;
        return;
    }
    int idx = blockIdx.x * 256 + threadIdx.x;
    if (idx < 8192) {
        int j = idx & 7, L = (idx >> 3) & 63, s = (idx >> 9) & 3, t = idx >> 11;
        int k = s * 32 + (L >> 4) * 8 + j;
        int c = t * 16 + (L & 15);
        W1g[idx] = (_Float16)W1[k * 64 + c];
    } else if (idx < 8192 + 5120) {
        int i2 = idx - 8192;
        int j = i2 & 7, L = (i2 >> 3) & 63, s = (i2 >> 9) & 1, u = i2 >> 10;
        int k = s * 32 + (L >> 4) * 8 + j;
        int c = (L & 15);
        float v;
        if (u < 4) v = W2[k * 64 + u * 16 + c];
        else v = (c < 6) ? W3[k * 6 + c] : 0.f;
        Bg[i2] = (_Float16)v;
    }
}

// XCD-sliced single-pass ELL build: rank comes from the atomic itself.
// slice = blockIdx&7 -> round-robin XCD mapping; each slice's cnt+ell working
// set (~25KB + ~1.2MB) stays resident in that XCD's L2 so writebacks merge.
__global__ __launch_bounds__(256) void k_scatter(
    const int* __restrict__ row, const int* __restrict__ col,
    int* __restrict__ cnt, int* __restrict__ ell, int E, int slice_sz) {
    int slice = blockIdx.x & 7;
    int lo = slice * slice_sz;
    int hi = lo + slice_sz;
    int nchunk = gridDim.x >> 3;
    int stride = nchunk * 256;
    int v0 = (blockIdx.x >> 3) * 256 + threadIdx.x;
    int nv = E >> 2;
    const int4* c4p = (const int4*)col;
    const int4* r4p = (const int4*)row;
    for (int v = v0; v < nv; v += stride) {
        int4 c4 = c4p[v];
        int4 r4 = r4p[v];
        if (c4.x >= lo && c4.x < hi) {
            int rk = atomicAdd(&cnt[c4.x], 1);
            if (rk < ELLW) ell[c4.x * ELLW + rk] = r4.x << 7;
        }
        if (c4.y >= lo && c4.y < hi) {
            int rk = atomicAdd(&cnt[c4.y], 1);
            if (rk < ELLW) ell[c4.y * ELLW + rk] = r4.y << 7;
        }
        if (c4.z >= lo && c4.z < hi) {
            int rk = atomicAdd(&cnt[c4.z], 1);
            if (rk < ELLW) ell[c4.z * ELLW + rk] = r4.z << 7;
        }
        if (c4.w >= lo && c4.w < hi) {
            int rk = atomicAdd(&cnt[c4.w], 1);
            if (rk < ELLW) ell[c4.w * ELLW + rk] = r4.w << 7;
        }
    }
    if ((blockIdx.x >> 3) == 0) {        // tail edges (E % 4)
        for (int e = (nv << 2) + threadIdx.x; e < E; e += 256) {
            int c = col[e];
            if (c >= lo && c < hi) {
                int rk = atomicAdd(&cnt[c], 1);
                if (rk < ELLW) ell[c * ELLW + rk] = row[e] << 7;
            }
        }
    }
}

// hs = (x @ W1) * dinv, via f16 MFMA. Block = 4 waves x 16 nodes = 64 nodes.
__global__ __launch_bounds__(256, 4) void k_gemm1(
    const float* __restrict__ x, const _Float16* __restrict__ W1g,
    const int* __restrict__ cnt, uint* __restrict__ hs,
    uint* __restrict__ h2s, int n) {
    int tid = threadIdx.x;
    if (blockIdx.x == 0) {               // zero rows for clamped gathers
        if (tid < 32) hs[(size_t)n * 32 + tid] = 0u;
        else if (tid < 64) h2s[(size_t)n * 32 + (tid - 32)] = 0u;
    }
    int lane = tid & 63, wid = tid >> 6;
    int m16 = lane & 15, quad = lane >> 4;
    int node0 = blockIdx.x * 64 + wid * 16;
    int arow = node0 + m16;
    if (arow >= n) arow = n - 1;
    const float* xr = x + (size_t)arow * 128;
    half8 A[4];
#pragma unroll
    for (int s = 0; s < 4; s++) {
        const float4* p = (const float4*)(xr + s * 32 + quad * 8);
        float4 f0 = p[0], f1 = p[1];
        half8 a;
        a[0] = (_Float16)f0.x; a[1] = (_Float16)f0.y;
        a[2] = (_Float16)f0.z; a[3] = (_Float16)f0.w;
        a[4] = (_Float16)f1.x; a[5] = (_Float16)f1.y;
        a[6] = (_Float16)f1.z; a[7] = (_Float16)f1.w;
        A[s] = a;
    }
    float dsc[4];
#pragma unroll
    for (int r = 0; r < 4; r++) {
        int nd = node0 + quad * 4 + r;
        dsc[r] = rsqrtf((float)(cnt[nd < n ? nd : n - 1] + 1));
    }
    const half8* Wv = (const half8*)W1g;
#pragma unroll
    for (int t = 0; t < 4; t++) {
        f32x4 acc = {0.f, 0.f, 0.f, 0.f};
#pragma unroll
        for (int s = 0; s < 4; s++)
            acc = __builtin_amdgcn_mfma_f32_16x16x32_f16(A[s], Wv[(t * 4 + s) * 64 + lane], acc, 0, 0, 0);
#pragma unroll
        for (int r = 0; r < 4; r++) {
            int nd = node0 + quad * 4 + r;
            float v = acc[r] * dsc[r];
            float vo = __shfl_xor(v, 1, 64);
            if (!(m16 & 1) && nd < n) {
                __half2 pk = __floats2half2_rn(v, vo);
                hs[(size_t)nd * 32 + t * 8 + (m16 >> 1)] = *(uint*)&pk;
            }
        }
    }
}

// ---------------------------------------------------------------------------
// v5 gather: lane = g*8 + l; l = byte-slice (16B of the 128B row), g = edge
// group in [0,8). Per 8-edge step per node: 1 idx load (4B, broadcast within
// group) + 1 row load (uint4) per lane. Depth-1 row prefetch (uA live, uB in
// flight). accv[p][c] accumulates comps 8*l + c. Cross-group reduce at end.
// ---------------------------------------------------------------------------
#define GATHER_PROLOG(SRC_T)                                                  \
    int st[4], P[4], nid[4];                                                  \
    int Pmax = 0;                                                             \
    _Pragma("unroll") for (int p = 0; p < 4; p++) {                           \
        int node = base + wid * 4 + p;                                        \
        if (node >= n) node = n - 1;                                          \
        nid[p] = node; st[p] = node * ELLW; P[p] = cnt[node];                 \
        Pmax = Pmax > P[p] ? Pmax : P[p];                                     \
    }                                                                         \
    Pmax = (Pmax + 7) & ~7;                                                   \
    auto ldix = [&](int p, int jb) -> int {                                   \
        int o = ell[st[p] + jb + g];                                          \
        return (jb + g < P[p]) ? o : zoff;                                    \
    };                                                                        \
    const char* hsb = (const char*)(SRC_T);                                   \
    float accv[4][8];                                                         \
    _Pragma("unroll") for (int p = 0; p < 4; p++) {                           \
        int sa = (g == 0) ? (nid[p] << 7) : zoff;                             \
        uint4 us = *(const uint4*)(hsb + sa + m16b);                          \
        float2 f;                                                             \
        f = __half22float2(*(__half2*)&us.x); accv[p][0] = f.x; accv[p][1] = f.y; \
        f = __half22float2(*(__half2*)&us.y); accv[p][2] = f.x; accv[p][3] = f.y; \
        f = __half22float2(*(__half2*)&us.z); accv[p][4] = f.x; accv[p][5] = f.y; \
        f = __half22float2(*(__half2*)&us.w); accv[p][6] = f.x; accv[p][7] = f.y; \
    }

#define CVT_ACC(p, U)                                                         \
    {                                                                         \
        float2 f;                                                             \
        f = __half22float2(*(__half2*)&U.x); accv[p][0] += f.x; accv[p][1] += f.y; \
        f = __half22float2(*(__half2*)&U.y); accv[p][2] += f.x; accv[p][3] += f.y; \
        f = __half22float2(*(__half2*)&U.z); accv[p][4] += f.x; accv[p][5] += f.y; \
        f = __half22float2(*(__half2*)&U.w); accv[p][6] += f.x; accv[p][7] += f.y; \
    }

#define GATHER_BODY16(SRC)                                                    \
    {                                                                         \
        int oB[4], oC[4];                                                     \
        uint4 uA[4], uB[4];                                                   \
        {                                                                     \
            int oA[4];                                                        \
            _Pragma("unroll") for (int p = 0; p < 4; p++) oA[p] = ldix(p, 0); \
            _Pragma("unroll") for (int p = 0; p < 4; p++) oB[p] = ldix(p, 8); \
            _Pragma("unroll") for (int p = 0; p < 4; p++)                     \
                uA[p] = *(const uint4*)(SRC + oA[p] + m16b);                  \
        }                                                                     \
        for (int jb = 0; jb < Pmax; jb += 8) {                                \
            _Pragma("unroll") for (int p = 0; p < 4; p++) oC[p] = ldix(p, jb + 16); \
            _Pragma("unroll") for (int p = 0; p < 4; p++)                     \
                uB[p] = *(const uint4*)(SRC + oB[p] + m16b);                  \
            _Pragma("unroll") for (int p = 0; p < 4; p++) CVT_ACC(p, uA[p])   \
            _Pragma("unroll") for (int p = 0; p < 4; p++) {                   \
                uA[p] = uB[p]; oB[p] = oC[p];                                 \
            }                                                                 \
        }                                                                     \
    }                                                                         \
    _Pragma("unroll") for (int p = 0; p < 4; p++)                             \
        _Pragma("unroll") for (int c = 0; c < 8; c++) {                       \
            float v = accv[p][c];                                             \
            v += __shfl_xor(v, 8, 64);                                        \
            v += __shfl_xor(v, 16, 64);                                       \
            v += __shfl_xor(v, 32, 64);                                       \
            accv[p][c] = v;                                                   \
        }

// conv1 + bias + LN + ReLU, then h2s & out2 via per-wave MFMA. No barriers.
__global__ __launch_bounds__(256, 4) void k_conv1_fused(
    const uint* __restrict__ hs, const int* __restrict__ ell,
    const int* __restrict__ cnt, const float* __restrict__ b1,
    const float* __restrict__ lnw_g, const float* __restrict__ lnb_g,
    const _Float16* __restrict__ Bg, const float* __restrict__ b3,
    uint* __restrict__ h2s, float* __restrict__ out2, int zoff, int n) {
    __shared__ _Float16 Y[4][16 * 72];   // per-wave A tile, stride 72
    int tid = threadIdx.x;
    int lane = tid & 63, wid = tid >> 6;
    int l = lane & 7, g = lane >> 3;
    int m16b = l * 16;
    {   // zero my wave's tile (rows 4..15 stay zero for the MFMA)
        float4 z = {0.f, 0.f, 0.f, 0.f};
        float4* yb = (float4*)Y[wid];
        for (int i = lane; i < 144; i += 64) yb[i] = z;
    }
    int base = blockIdx.x * 16;
    GATHER_PROLOG(hs)
    GATHER_BODY16(hsb)

    // LN + ReLU: lane owns comps 8l..8l+7 (duplicated across g); row reduce
    // is xor 1,2,4 (l bits). Write y rows (f16, 16B/lane from g==0) to Y tile.
    float4 bvlo = ((const float4*)b1)[2 * l], bvhi = ((const float4*)b1)[2 * l + 1];
    float4 lwlo = ((const float4*)lnw_g)[2 * l], lwhi = ((const float4*)lnw_g)[2 * l + 1];
    float4 lblo = ((const float4*)lnb_g)[2 * l], lbhi = ((const float4*)lnb_g)[2 * l + 1];
    float dcs[4];
#pragma unroll
    for (int p = 0; p < 4; p++) {
        float dc = rsqrtf((float)(P[p] + 1));
        dcs[p] = dc;
        float v[8];
        v[0] = fmaf(dc, accv[p][0], bvlo.x); v[1] = fmaf(dc, accv[p][1], bvlo.y);
        v[2] = fmaf(dc, accv[p][2], bvlo.z); v[3] = fmaf(dc, accv[p][3], bvlo.w);
        v[4] = fmaf(dc, accv[p][4], bvhi.x); v[5] = fmaf(dc, accv[p][5], bvhi.y);
        v[6] = fmaf(dc, accv[p][6], bvhi.z); v[7] = fmaf(dc, accv[p][7], bvhi.w);
        float s = ((v[0] + v[1]) + (v[2] + v[3])) + ((v[4] + v[5]) + (v[6] + v[7]));
        s += __shfl_xor(s, 1, 64); s += __shfl_xor(s, 2, 64); s += __shfl_xor(s, 4, 64);
        float mu = s * (1.f / 64.f);
        float d[8], q = 0.f;
#pragma unroll
        for (int c = 0; c < 8; c++) { d[c] = v[c] - mu; q += d[c] * d[c]; }
        q += __shfl_xor(q, 1, 64); q += __shfl_xor(q, 2, 64); q += __shfl_xor(q, 4, 64);
        float rstd = rsqrtf(q * (1.f / 64.f) + 1e-5f);
        float y[8];
        y[0] = fmaxf(fmaf(d[0] * rstd, lwlo.x, lblo.x), 0.f);
        y[1] = fmaxf(fmaf(d[1] * rstd, lwlo.y, lblo.y), 0.f);
        y[2] = fmaxf(fmaf(d[2] * rstd, lwlo.z, lblo.z), 0.f);
        y[3] = fmaxf(fmaf(d[3] * rstd, lwlo.w, lblo.w), 0.f);
        y[4] = fmaxf(fmaf(d[4] * rstd, lwhi.x, lbhi.x), 0.f);
        y[5] = fmaxf(fmaf(d[5] * rstd, lwhi.y, lbhi.y), 0.f);
        y[6] = fmaxf(fmaf(d[6] * rstd, lwhi.z, lbhi.z), 0.f);
        y[7] = fmaxf(fmaf(d[7] * rstd, lwhi.w, lbhi.w), 0.f);
        if (g == 0) {                    // 8 lanes x 16B = full 128B row
            __half2 pk0 = __floats2half2_rn(y[0], y[1]);
            __half2 pk1 = __floats2half2_rn(y[2], y[3]);
            __half2 pk2 = __floats2half2_rn(y[4], y[5]);
            __half2 pk3 = __floats2half2_rn(y[6], y[7]);
            uint4 pk;
            pk.x = *(uint*)&pk0; pk.y = *(uint*)&pk1;
            pk.z = *(uint*)&pk2; pk.w = *(uint*)&pk3;
            *(uint4*)&Y[wid][p * 72 + 8 * l] = pk;   // byte p*144+16l, 16B-aligned
        }
    }
    // same-wave LDS producer/consumer: lgkmcnt wait only, no barrier
    int m16 = lane & 15, quad = lane >> 4;
    half8 a0 = *(const half8*)&Y[wid][m16 * 72 + quad * 8];
    half8 a1 = *(const half8*)&Y[wid][m16 * 72 + 32 + quad * 8];
    const half8* Bv = (const half8*)Bg;
    _Float16* h2h = (_Float16*)h2s;
#pragma unroll
    for (int t = 0; t < 4; t++) {        // h2 = y @ W2 (4 col tiles)
        f32x4 acc2 = {0.f, 0.f, 0.f, 0.f};
        acc2 = __builtin_amdgcn_mfma_f32_16x16x32_f16(a0, Bv[(t * 2 + 0) * 64 + lane], acc2, 0, 0, 0);
        acc2 = __builtin_amdgcn_mfma_f32_16x16x32_f16(a1, Bv[(t * 2 + 1) * 64 + lane], acc2, 0, 0, 0);
#pragma unroll
        for (int r = 0; r < 4; r++) {    // C row quad*4+r: real rows live in quad 0
            int nodep = base + wid * 4 + r;
            if (quad == 0 && nodep < n)
                h2h[(size_t)nodep * 64 + t * 16 + m16] = (_Float16)(acc2[r] * dcs[r]);
        }
    }
    {                                    // out2 = sigmoid(y @ W3 + b3)
        f32x4 acc2 = {0.f, 0.f, 0.f, 0.f};
        acc2 = __builtin_amdgcn_mfma_f32_16x16x32_f16(a0, Bv[8 * 64 + lane], acc2, 0, 0, 0);
        acc2 = __builtin_amdgcn_mfma_f32_16x16x32_f16(a1, Bv[9 * 64 + lane], acc2, 0, 0, 0);
        float bb = b3[m16 < 6 ? m16 : 0];
#pragma unroll
        for (int r = 0; r < 4; r++) {
            int nodep = base + wid * 4 + r;
            if (quad == 0 && m16 < 6 && nodep < n)
                out2[(size_t)nodep * 6 + m16] = 1.f / (1.f + __expf(-(acc2[r] + bb)));
        }
    }
}

// conv2: out1 = dc * (self + sum(h2s[slice])) + b2.
__global__ __launch_bounds__(256, 4) void k_conv2(
    const uint* __restrict__ h2s, const int* __restrict__ ell,
    const int* __restrict__ cnt, const float* __restrict__ b2,
    float* __restrict__ out1, int zoff, int n) {
    int tid = threadIdx.x;
    int lane = tid & 63, wid = tid >> 6;
    int l = lane & 7, g = lane >> 3;
    int m16b = l * 16;
    int base = blockIdx.x * 16;
    GATHER_PROLOG(h2s)
    GATHER_BODY16(hsb)

    float4 b2lo = ((const float4*)b2)[2 * l], b2hi = ((const float4*)b2)[2 * l + 1];
#pragma unroll
    for (int p = 0; p < 4; p++) {
        int node = base + wid * 4 + p;
        if (g == 0 && node < n) {
            float dc = rsqrtf((float)(P[p] + 1));
            float4 r0, r1;
            r0.x = fmaf(dc, accv[p][0], b2lo.x);
            r0.y = fmaf(dc, accv[p][1], b2lo.y);
            r0.z = fmaf(dc, accv[p][2], b2lo.z);
            r0.w = fmaf(dc, accv[p][3], b2lo.w);
            r1.x = fmaf(dc, accv[p][4], b2hi.x);
            r1.y = fmaf(dc, accv[p][5], b2hi.y);
            r1.z = fmaf(dc, accv[p][6], b2hi.z);
            r1.w = fmaf(dc, accv[p][7], b2hi.w);
            ((float4*)out1)[(size_t)node * 16 + 2 * l] = r0;
            ((float4*)out1)[(size_t)node * 16 + 2 * l + 1] = r1;
        }
    }
}

extern "C" void kernel_launch(void* const* d_in, const int* in_sizes, int n_in,
                              void* d_out, int out_size, void* d_ws, size_t ws_size,
                              hipStream_t stream) {
    const float* x   = (const float*)d_in[0];
    const int*   ei  = (const int*)d_in[1];
    const float* W1  = (const float*)d_in[2];
    const float* b1  = (const float*)d_in[3];
    const float* lnw = (const float*)d_in[4];
    const float* lnb = (const float*)d_in[5];
    const float* W2  = (const float*)d_in[6];
    const float* b2  = (const float*)d_in[7];
    const float* W3  = (const float*)d_in[8];
    const float* b3  = (const float*)d_in[9];

    int n = in_sizes[0] / 128;
    int E = in_sizes[1] / 2;
    const int* row = ei;        // sources
    const int* col = ei + E;    // targets

    char* ws = (char*)d_ws;
    size_t off = 0;
    auto carve = [&](size_t bytes) -> char* {
        char* p = ws + off;
        off = (off + bytes + 255) & ~(size_t)255;
        return p;
    };
    int*   cnt  = (int*)carve(4 * (size_t)n);
    int*   ell  = (int*)carve(4 * ((size_t)n * ELLW + 256));  // +margin for prefetch
    uint*  hs   = (uint*)carve(128 * ((size_t)n + 1));        // +1 zero row
    uint*  h2s  = (uint*)carve(128 * ((size_t)n + 1));
    _Float16* W1g = (_Float16*)carve(2 * 8192);
    _Float16* Bg  = (_Float16*)carve(2 * 5120);

    float* out1 = (float*)d_out;
    float* out2 = out1 + (size_t)n * 64;
    int zero_off = n << 7;
    int slice_sz = (n + 7) / 8;          // contiguous node slice per XCD

    k_setup<<<52 + (n + 255) / 256, 256, 0, stream>>>(W1, W2, W3, W1g, Bg, cnt, n);
    // 8 slices x 256 edge-chunks; blockIdx&7 = slice -> XCD round-robin
    k_scatter<<<8 * 256, 256, 0, stream>>>(row, col, cnt, ell, E, slice_sz);
    k_gemm1<<<(n + 63) / 64, 256, 0, stream>>>(x, W1g, cnt, hs, h2s, n);
    k_conv1_fused<<<(n + 15) / 16, 256, 0, stream>>>(hs, ell, cnt,
                                                     b1, lnw, lnb, Bg, b3,
                                                     h2s, out2, zero_off, n);
    k_conv2<<<(n + 15) / 16, 256, 0, stream>>>(h2s, ell, cnt, b2,
                                               out1, zero_off, n);
}